// Round 13
// baseline (42.711 us; speedup 1.0000x reference)
//
#include <hip/hip_runtime.h>
#include <hip/hip_bf16.h>

typedef int i32x4 __attribute__((ext_vector_type(4)));
typedef int i32x8 __attribute__((ext_vector_type(8)));
typedef float f32x4 __attribute__((ext_vector_type(4)));

#define KD 768
#define BDIM 4096
#define NT 6             // K-tiles of BK=128
#define E8M0_1_8TH 124   // 2^(124-127) = 1/8

#define GLOAD_LDS16(gptr, lptr)                                             \
    __builtin_amdgcn_global_load_lds(                                       \
        (const __attribute__((address_space(1))) unsigned int*)(gptr),      \
        (__attribute__((address_space(3))) unsigned int*)(lptr), 16, 0, 0)

#define FBAR() asm volatile("s_barrier" ::: "memory")

__device__ inline unsigned char f32_to_e4m3(float f) {
    int p = __builtin_amdgcn_cvt_pk_fp8_f32(f, f, 0, false);
    return (unsigned char)(p & 0xFF);
}

// ---------------- Kernel 1: row-normalize fp32 -> fp8 e4m3, pre-scaled x8 ----------------
__global__ __launch_bounds__(256) void normalize_rows_fp8(
    const float* __restrict__ x, unsigned char* __restrict__ xn)
{
    const int row = blockIdx.x;
    const int t = threadIdx.x;
    const float* xr = x + (long)row * KD;

    float v[3];
    float ss = 0.f;
#pragma unroll
    for (int i = 0; i < 3; ++i) {
        v[i] = xr[t + 256 * i];
        ss += v[i] * v[i];
    }
#pragma unroll
    for (int off = 32; off > 0; off >>= 1) ss += __shfl_down(ss, off);
    __shared__ float wss[4];
    const int lane = t & 63, wv = t >> 6;
    if (lane == 0) wss[wv] = ss;
    __syncthreads();
    const float tot = wss[0] + wss[1] + wss[2] + wss[3];
    const float inv = 8.0f / fmaxf(sqrtf(tot), 1e-8f);
#pragma unroll
    for (int i = 0; i < 3; ++i)
        xn[(long)row * KD + t + 256 * i] = f32_to_e4m3(v[i] * inv);
}

// ---------------- Kernel 2: 128x128-tile MX-fp8 GEMM, staggered 4-round grid ----------
// STRUCTURE vs R10-12: no streaming. 1024 blocks (32x32 tiles) = 2 blocks/CU x 4
// sequential rounds. Block: pure-read K-loop (6 x BK=128, R7 2-barrier skeleton,
// R9 swizzle) then pure-write 128 KB burst (1 KB runs per row). Staggered block
// completion overlaps one block's write burst with the co-resident block's compute;
// only the last round's ~33 MB is an exposed tail.
// 8 waves (2M x 4N): wave = 64 rows x 32 cols; per K-tile per wave: 12 ds_read_b128,
// 8 MFMA(16x16x128); acc = 8 f32x4 = 32 VGPR. LDS 64 KB (2x16KB A + 2x16KB B).
__global__ __launch_bounds__(512, 4) void sim_gemm_tile(
    const unsigned char* __restrict__ Xn,
    const float* __restrict__ fcw, const float* __restrict__ fcb,
    float* __restrict__ out)
{
    __shared__ __align__(16) unsigned char Ab[2][128 * 128];  // 2 x 16 KB
    __shared__ __align__(16) unsigned char Bb[2][128 * 128];  // 2 x 16 KB

    const int tid = threadIdx.x;
    const int wv  = tid >> 6;    // 0..7
    const int ln  = tid & 63;
    const int wm  = wv >> 2;     // 0..1 (M group, 64 rows)
    const int wn  = wv & 3;      // 0..3 (N group, 32 cols)
    const int fr  = ln & 15;
    const int q   = ln >> 4;     // 0..3

    const int bj = blockIdx.x;   // 0..31 col tile
    const int bi = blockIdx.y;   // 0..31 row tile
    const long Arow0 = (long)bi * 128;
    const long Brow0 = (long)bj * 128;

    // --- staging precompute: tile = 16 KB = 2 chunks of 8 KB (512 thr x 16 B).
    // Dest byte d = i*8192 + tid*16 -> row = d>>7, kbyte = d&127.
    // Source kcol = kbyte ^ ((row&7)<<4)  (involution within the 128-B row).
    int srow[2], skcol[2];
#pragma unroll
    for (int i = 0; i < 2; ++i) {
        const int d = i * 8192 + tid * 16;
        srow[i]  = d >> 7;                         // 0..127
        skcol[i] = (d & 127) ^ ((srow[i] & 7) << 4);
    }

#define ISSUE_TILE(tt) do {                                                  \
        _Pragma("unroll")                                                    \
        for (int i_ = 0; i_ < 2; ++i_) {                                     \
            const unsigned char* ga_ = Xn + (Arow0 + srow[i_]) * (long)KD    \
                                       + (tt) * 128 + skcol[i_];             \
            GLOAD_LDS16(ga_, &Ab[(tt) & 1][i_ * 8192 + wv * 1024]);          \
            const unsigned char* gb_ = Xn + (Brow0 + srow[i_]) * (long)KD    \
                                       + (tt) * 128 + skcol[i_];             \
            GLOAD_LDS16(gb_, &Bb[(tt) & 1][i_ * 8192 + wv * 1024]);          \
        }                                                                    \
    } while (0)

    // --- ds_read addressing (R9 scheme): frag row uses fr; lane k-block q.
    //     byte = row*128 + (kb ^ ((fr&7)<<4)), kb in {q*32, q*32+16}
    const int q32 = q << 5;
    const int swz = (ln & 7) << 4;
    const int kb0 = (q32)      ^ swz;
    const int kb1 = (q32 + 16) ^ swz;

    f32x4 acc[4][2] = {};
    i32x8 av[4];

#define LDA_ALL() do {                                                       \
        _Pragma("unroll")                                                    \
        for (int mf = 0; mf < 4; ++mf) {                                     \
            const int r_ = (wm * 64 + mf * 16 + fr) * 128;                   \
            i32x4 lo = *(const i32x4*)&Ab[bb][r_ + kb0];                     \
            i32x4 hi = *(const i32x4*)&Ab[bb][r_ + kb1];                     \
            av[mf] = __builtin_shufflevector(lo, hi, 0, 1, 2, 3, 4, 5, 6, 7);\
        }                                                                    \
    } while (0)

#define DO_NF(nf) do {                                                       \
        const int r_ = (wn * 32 + (nf) * 16 + fr) * 128;                     \
        i32x4 lo = *(const i32x4*)&Bb[bb][r_ + kb0];                         \
        i32x4 hi = *(const i32x4*)&Bb[bb][r_ + kb1];                         \
        i32x8 bv = __builtin_shufflevector(lo, hi, 0, 1, 2, 3, 4, 5, 6, 7);  \
        __builtin_amdgcn_s_setprio(1);                                       \
        _Pragma("unroll")                                                    \
        for (int mf = 0; mf < 4; ++mf)                                       \
            acc[mf][nf] = __builtin_amdgcn_mfma_scale_f32_16x16x128_f8f6f4(  \
                av[mf], bv, acc[mf][nf], 0, 0,                               \
                0, E8M0_1_8TH, 0, E8M0_1_8TH);                               \
        __builtin_amdgcn_s_setprio(0);                                       \
    } while (0)

    // --- prologue: stage tile0 + tile1; tile0 landed, tile1 (4 loads) in flight ---
    ISSUE_TILE(0);
    ISSUE_TILE(1);
    asm volatile("s_waitcnt vmcnt(4)" ::: "memory");
    FBAR();

    for (int t = 0; t < NT; ++t) {
        const int bb = t & 1;

        LDA_ALL();
        DO_NF(0); DO_NF(1);

        if (t + 1 == NT) break;

        FBAR();  // all waves done reading bb
        if (t + 2 < NT) {
            ISSUE_TILE(t + 2);   // 4 loads into bb (safe to overwrite)
            asm volatile("s_waitcnt vmcnt(4)" ::: "memory");  // t+1 landed
        } else {
            asm volatile("s_waitcnt vmcnt(0)" ::: "memory");
        }
        FBAR();
    }

    // --- epilogue: pure-write burst. Rows outer, nf inner -> adjacent 128 B
    //     segments back-to-back; block covers 1 KB contiguous per output row.
    const float w0 = fcw[0], w1 = fcw[1];
    const float c0 = fcb[0], c1 = fcb[1];
    const long row0 = Arow0 + wm * 64 + q * 4;
    const int  col0 = (int)Brow0 + wn * 32 + fr;
#pragma unroll
    for (int mf = 0; mf < 4; ++mf)
#pragma unroll
        for (int rr = 0; rr < 4; ++rr) {
            const long row = row0 + mf * 16 + rr;
#pragma unroll
            for (int nf = 0; nf < 2; ++nf) {
                const float sv = acc[mf][nf][rr];
                *(float2*)&out[(row * BDIM + col0 + nf * 16) * 2] =
                    make_float2(fmaf(sv, w0, c0), fmaf(sv, w1, c1));
            }
        }

#undef ISSUE_TILE
#undef LDA_ALL
#undef DO_NF
}

extern "C" void kernel_launch(void* const* d_in, const int* in_sizes, int n_in,
                              void* d_out, int out_size, void* d_ws, size_t ws_size,
                              hipStream_t stream) {
    const float* x   = (const float*)d_in[0];
    const float* fcw = (const float*)d_in[1];
    const float* fcb = (const float*)d_in[2];
    float* out = (float*)d_out;

    unsigned char* xn = (unsigned char*)d_ws;  // 4096*768*1B = 3.1 MB

    normalize_rows_fp8<<<BDIM, 256, 0, stream>>>(x, xn);

    dim3 grid(32, 32);  // 1024 tiles = 2/CU x 4 rounds
    sim_gemm_tile<<<grid, 512, 0, stream>>>(xn, fcw, fcb, out);
}